// Round 1
// baseline (186.363 us; speedup 1.0000x reference)
//
#include <hip/hip_runtime.h>

#define N_NODES 100000
#define BATCH   64
#define MID     32

// out[:,0,n,:] = Wp · [value[(n-1)%N], node[n]],  value = MLP(edge) · node  (softmax is
// degenerate: dst is a bijection so alpha == 1 exactly; q/Wq/key unused).
__global__ __launch_bounds__(256) void xattn_kernel(
    const float* __restrict__ in,
    const float* __restrict__ W1, const float* __restrict__ b1,
    const float* __restrict__ W2, const float* __restrict__ b2,
    const float* __restrict__ W3, const float* __restrict__ Wp,
    float* __restrict__ out)
{
    int idx = blockIdx.x * blockDim.x + threadIdx.x;
    if (idx >= BATCH * N_NODES) return;
    int b = idx / N_NODES;
    int n = idx - b * N_NODES;
    int p = (n == 0) ? (N_NODES - 1) : (n - 1);

    const float* inb  = in  + (size_t)b * 3u * N_NODES * 3u;
    float*       outb = out + (size_t)b * 3u * N_NODES * 3u;

    // channel 0 = node, channel 2 = edge
    const float* edgep = inb + ((size_t)2 * N_NODES + p) * 3;
    const float* nodep = inb + (size_t)p * 3;
    const float* noden = inb + (size_t)n * 3;

    float e0 = edgep[0], e1 = edgep[1], e2 = edgep[2];
    float p0 = nodep[0], p1 = nodep[1], p2 = nodep[2];
    float q0 = noden[0], q1 = noden[1], q2 = noden[2];

    // ---- MLP on edge[p] (weights are wave-uniform -> s_load + SGPR-operand fmac) ----
    float h1[MID];
#pragma unroll
    for (int j = 0; j < MID; ++j) {
        float v = b1[j];
        v = fmaf(e0, W1[0 * MID + j], v);
        v = fmaf(e1, W1[1 * MID + j], v);
        v = fmaf(e2, W1[2 * MID + j], v);
        h1[j] = v > 0.f ? v : 0.f;
    }

    float h2[MID];
#pragma unroll
    for (int j = 0; j < MID; ++j) h2[j] = b2[j];
#pragma unroll
    for (int i = 0; i < MID; ++i) {
        float hi = h1[i];
#pragma unroll
        for (int j = 0; j < MID; ++j)
            h2[j] = fmaf(hi, W2[i * MID + j], h2[j]);
    }

    float r0 = 0.f, r1 = 0.f, r2 = 0.f;
#pragma unroll
    for (int i = 0; i < MID; ++i) {
        float hi = h2[i] > 0.f ? h2[i] : 0.f;
        r0 = fmaf(hi, W3[i * 6 + 0], r0);
        r1 = fmaf(hi, W3[i * 6 + 1], r1);
        r2 = fmaf(hi, W3[i * 6 + 2], r2);
    }

    // value at src position p, landing at output position n (z[b,n] = value[b,p])
    float z = r0 * p0 + r1 * p1 + r2 * p2;

    // out0[o] = Wp[o,0]*z + Wp[o,1]*node_n.x + Wp[o,2]*node_n.y + Wp[o,3]*node_n.z
    float* o0 = outb + (size_t)n * 3;
#pragma unroll
    for (int o = 0; o < 3; ++o) {
        float v = Wp[o * 4 + 0] * z;
        v = fmaf(Wp[o * 4 + 1], q0, v);
        v = fmaf(Wp[o * 4 + 2], q1, v);
        v = fmaf(Wp[o * 4 + 3], q2, v);
        o0[o] = v;
    }

    // copy channels 1 and 2 verbatim
    const float* c1 = inb + ((size_t)1 * N_NODES + n) * 3;
    const float* c2 = inb + ((size_t)2 * N_NODES + n) * 3;
    float* o1 = outb + ((size_t)1 * N_NODES + n) * 3;
    float* o2 = outb + ((size_t)2 * N_NODES + n) * 3;
    o1[0] = c1[0]; o1[1] = c1[1]; o1[2] = c1[2];
    o2[0] = c2[0]; o2[1] = c2[1]; o2[2] = c2[2];
}

extern "C" void kernel_launch(void* const* d_in, const int* in_sizes, int n_in,
                              void* d_out, int out_size, void* d_ws, size_t ws_size,
                              hipStream_t stream) {
    const float* in = (const float*)d_in[0];
    const float* W1 = (const float*)d_in[1];
    const float* b1 = (const float*)d_in[2];
    const float* W2 = (const float*)d_in[3];
    const float* b2 = (const float*)d_in[4];
    const float* W3 = (const float*)d_in[5];
    // d_in[6] = Wq — provably unused (softmax weights are exactly 1)
    const float* Wp = (const float*)d_in[7];
    float* out = (float*)d_out;

    int total  = BATCH * N_NODES;
    int blocks = (total + 255) / 256;
    hipLaunchKernelGGL(xattn_kernel, dim3(blocks), dim3(256), 0, stream,
                       in, W1, b1, W2, b2, W3, Wp, out);
}

// Round 3
// 159.367 us; speedup vs baseline: 1.1694x; 1.1694x over previous
//
#include <hip/hip_runtime.h>

#define N_NODES 100000
#define BATCH   64
#define MID     32

typedef __attribute__((ext_vector_type(2))) __fp16 half2v;
union H2U { half2v h; unsigned int u; };

// Pre-pack W2 (32x32 f32) into f16 pairs along K: w2p[kk*32+j] = pack(W2[2kk][j], W2[2kk+1][j]).
// Runs once per launch into d_ws so the main kernel's weight reads stay wave-uniform (s_load).
__global__ void pack_w2(const float* __restrict__ W2, unsigned int* __restrict__ w2p) {
    int t = threadIdx.x;
    if (t < (MID / 2) * MID) {
        int kk = t >> 5, j = t & 31;
        H2U p;
        p.h = __builtin_amdgcn_cvt_pkrtz(W2[(2 * kk) * MID + j], W2[(2 * kk + 1) * MID + j]);
        w2p[t] = p.u;
    }
}

// out[:,0,n,:] = Wp . [value[(n-1)%N], node[n]],  value = MLP(edge) . node.
// Softmax is degenerate (dst is a bijection -> alpha == 1 exactly); q/Wq/key unused.
// Layer 2 (32x32) runs as v_dot2_f32_f16 (2 FMA/instr); layer 3 fused into the j-loop.
__global__ __launch_bounds__(256) void xattn_kernel(
    const float* __restrict__ in,
    const float* __restrict__ W1, const float* __restrict__ b1,
    const unsigned int* __restrict__ w2p, const float* __restrict__ b2,
    const float* __restrict__ W3, const float* __restrict__ Wp,
    float* __restrict__ out)
{
    int idx = blockIdx.x * blockDim.x + threadIdx.x;
    if (idx >= BATCH * N_NODES) return;
    int b = idx / N_NODES;
    int n = idx - b * N_NODES;
    int p = (n == 0) ? (N_NODES - 1) : (n - 1);

    const float* inb  = in  + (size_t)b * 3u * N_NODES * 3u;
    float*       outb = out + (size_t)b * 3u * N_NODES * 3u;

    // channel 0 = node, channel 2 = edge
    const float* edgep = inb + ((size_t)2 * N_NODES + p) * 3;
    const float* nodep = inb + (size_t)p * 3;
    const float* noden = inb + (size_t)n * 3;

    float e0 = edgep[0], e1 = edgep[1], e2 = edgep[2];
    float p0 = nodep[0], p1 = nodep[1], p2 = nodep[2];
    float q0 = noden[0], q1 = noden[1], q2 = noden[2];

    // ---- layer 1 (K=3, f32) + relu + pack to f16 pairs ----
    unsigned int h1p[MID / 2];
#pragma unroll
    for (int kk = 0; kk < MID / 2; ++kk) {
        int j0 = 2 * kk, j1 = 2 * kk + 1;
        float v0 = fmaf(e0, W1[0 * MID + j0],
                   fmaf(e1, W1[1 * MID + j0],
                   fmaf(e2, W1[2 * MID + j0], b1[j0])));
        float v1 = fmaf(e0, W1[0 * MID + j1],
                   fmaf(e1, W1[1 * MID + j1],
                   fmaf(e2, W1[2 * MID + j1], b1[j1])));
        v0 = fmaxf(v0, 0.f);
        v1 = fmaxf(v1, 0.f);
        H2U pk;
        pk.h = __builtin_amdgcn_cvt_pkrtz(v0, v1);
        h1p[kk] = pk.u;
    }

    // ---- layer 2 (dot2 f16, f32 accum) fused with layer 3 ----
    float r0 = 0.f, r1 = 0.f, r2 = 0.f;
#pragma unroll
    for (int j = 0; j < MID; ++j) {
        float acc = b2[j];
#pragma unroll
        for (int kk = 0; kk < MID / 2; ++kk) {
            H2U a; a.u = h1p[kk];
            H2U w; w.u = w2p[kk * MID + j];
#if __has_builtin(__builtin_amdgcn_fdot2)
            acc = __builtin_amdgcn_fdot2(a.h, w.h, acc, false);
#else
            acc = fmaf((float)a.h[0], (float)w.h[0], acc);
            acc = fmaf((float)a.h[1], (float)w.h[1], acc);
#endif
        }
        acc = fmaxf(acc, 0.f);
        r0 = fmaf(acc, W3[j * 6 + 0], r0);
        r1 = fmaf(acc, W3[j * 6 + 1], r1);
        r2 = fmaf(acc, W3[j * 6 + 2], r2);
    }

    // value at src position p lands at output position n (alpha == 1)
    float z = r0 * p0 + r1 * p1 + r2 * p2;

    float* o0 = outb + (size_t)n * 3;
#pragma unroll
    for (int o = 0; o < 3; ++o) {
        float v = Wp[o * 4 + 0] * z;
        v = fmaf(Wp[o * 4 + 1], q0, v);
        v = fmaf(Wp[o * 4 + 2], q1, v);
        v = fmaf(Wp[o * 4 + 3], q2, v);
        o0[o] = v;
    }

    // copy channels 1 and 2 verbatim
    const float* c1 = inb + ((size_t)1 * N_NODES + n) * 3;
    const float* c2 = inb + ((size_t)2 * N_NODES + n) * 3;
    float* o1 = outb + ((size_t)1 * N_NODES + n) * 3;
    float* o2 = outb + ((size_t)2 * N_NODES + n) * 3;
    o1[0] = c1[0]; o1[1] = c1[1]; o1[2] = c1[2];
    o2[0] = c2[0]; o2[1] = c2[1]; o2[2] = c2[2];
}

extern "C" void kernel_launch(void* const* d_in, const int* in_sizes, int n_in,
                              void* d_out, int out_size, void* d_ws, size_t ws_size,
                              hipStream_t stream) {
    const float* in = (const float*)d_in[0];
    const float* W1 = (const float*)d_in[1];
    const float* b1 = (const float*)d_in[2];
    const float* W2 = (const float*)d_in[3];
    const float* b2 = (const float*)d_in[4];
    const float* W3 = (const float*)d_in[5];
    // d_in[6] = Wq — provably unused (softmax weights are exactly 1)
    const float* Wp = (const float*)d_in[7];
    float* out = (float*)d_out;

    unsigned int* w2p = (unsigned int*)d_ws;  // 512 * 4 B = 2 KB scratch
    hipLaunchKernelGGL(pack_w2, dim3(1), dim3(512), 0, stream, W2, w2p);

    int total  = BATCH * N_NODES;
    int blocks = (total + 255) / 256;
    hipLaunchKernelGGL(xattn_kernel, dim3(blocks), dim3(256), 0, stream,
                       in, W1, b1, w2p, b2, W3, Wp, out);
}

// Round 4
// 110.270 us; speedup vs baseline: 1.6901x; 1.4452x over previous
//
#include <hip/hip_runtime.h>

#define N_NODES 100000
#define BATCH   64
#define MID     32
#define LSTRIDE 112   // LDS row stride bytes: 16B-aligned; 4-row step = 112 dw = 16 mod 32 -> bank-friendly

typedef __attribute__((ext_vector_type(2))) __fp16 h2v;
typedef _Float16 __attribute__((ext_vector_type(8))) f16x8;
typedef float __attribute__((ext_vector_type(4))) f32x4;

union H2U  { h2v h; unsigned int u; };
union U4H8 { uint4 u; f16x8 h; };

// Pack W2 (32x32) into 2 col-tile B-fragments and W3 (32x6, cols 0..2) into 1 B-fragment,
// laid out per-lane so the main kernel reads one dwordx4 per fragment.
// Fragment layout (mfma_f32_16x16x32_f16 B): col j = lane&15 (+16*tile), k = (lane>>4)*8 + m.
__global__ void prep_weights(const float* __restrict__ W2, const float* __restrict__ W3,
                             uint4* __restrict__ wf) {
    int t = threadIdx.x;           // 192 threads
    if (t >= 192) return;
    int grp = t >> 6;              // 0,1: W2 col-tiles; 2: W3
    int l = t & 63;
    int k0 = (l >> 4) * 8;
    unsigned int pk[4];
    if (grp < 2) {
        int j = (l & 15) + 16 * grp;
#pragma unroll
        for (int m = 0; m < 4; ++m) {
            H2U a;
            a.h = __builtin_amdgcn_cvt_pkrtz(W2[(k0 + 2*m) * MID + j],
                                             W2[(k0 + 2*m + 1) * MID + j]);
            pk[m] = a.u;
        }
    } else {
        int j = l & 15;
#pragma unroll
        for (int m = 0; m < 4; ++m) {
            float x0 = (j < 3) ? W3[(k0 + 2*m) * 6 + j] : 0.f;
            float x1 = (j < 3) ? W3[(k0 + 2*m + 1) * 6 + j] : 0.f;
            H2U a; a.h = __builtin_amdgcn_cvt_pkrtz(x0, x1);
            pk[m] = a.u;
        }
    }
    wf[grp * 64 + l] = make_uint4(pk[0], pk[1], pk[2], pk[3]);
}

// Softmax is degenerate (dst bijection -> alpha == 1 exactly); q/Wq/key unused.
// Per wave: 64 consecutive positions. Scalar layer-1 -> LDS transpose -> MFMA layer-2
// -> LDS transpose -> MFMA layer-3 -> LDS gather -> scalar tail.
__global__ __launch_bounds__(256) void xattn_kernel(
    const float* __restrict__ in,
    const float* __restrict__ W1, const float* __restrict__ b1,
    const float* __restrict__ b2, const uint4* __restrict__ wf,
    const float* __restrict__ Wp,
    float* __restrict__ out)
{
    __shared__ uint4 ldsbuf[4 * 64 * LSTRIDE / 16];   // 28672 B, 7168 per wave
    int tid  = threadIdx.x;
    int lane = tid & 63;
    int wave = tid >> 6;
    char* L = (char*)ldsbuf + wave * (64 * LSTRIDE);

    int idx = blockIdx.x * 256 + tid;                 // grid covers exactly B*N
    int b = idx / N_NODES;
    int n = idx - b * N_NODES;
    int p = (n == 0) ? (N_NODES - 1) : (n - 1);

    const float* inb  = in  + (size_t)b * (3u * N_NODES * 3u);
    float*       outb = out + (size_t)b * (3u * N_NODES * 3u);

    const float* ep  = inb + ((size_t)2 * N_NODES + p) * 3;  // edge[p]
    const float* np_ = inb + (size_t)p * 3;                  // node[p]
    const float* nn_ = inb + (size_t)n * 3;                  // node[n]
    const float* c1p = inb + ((size_t)N_NODES + n) * 3;
    const float* c2p = inb + ((size_t)2 * N_NODES + n) * 3;

    float e0 = ep[0],  e1 = ep[1],  e2 = ep[2];
    float pp0 = np_[0], pp1 = np_[1], pp2 = np_[2];
    float qn0 = nn_[0], qn1 = nn_[1], qn2 = nn_[2];

    // channel 1/2 pass-through, done early to free registers
    {
        float c10 = c1p[0], c11 = c1p[1], c12 = c1p[2];
        float c20 = c2p[0], c21 = c2p[1], c22 = c2p[2];
        float* o1 = outb + ((size_t)N_NODES + n) * 3;
        float* o2 = outb + ((size_t)2 * N_NODES + n) * 3;
        o1[0] = c10; o1[1] = c11; o1[2] = c12;
        o2[0] = c20; o2[1] = c21; o2[2] = c22;
    }

    // ---- phase 1: scalar layer-1 (K=3, uniform weights in SGPRs), relu, pack f16 ----
    unsigned int hp[16];
#pragma unroll
    for (int m = 0; m < 16; ++m) {
        int j0 = 2*m, j1 = 2*m + 1;
        float v0 = fmaf(e0, W1[j0], fmaf(e1, W1[MID + j0], fmaf(e2, W1[2*MID + j0], b1[j0])));
        float v1 = fmaf(e0, W1[j1], fmaf(e1, W1[MID + j1], fmaf(e2, W1[2*MID + j1], b1[j1])));
        v0 = fmaxf(v0, 0.f); v1 = fmaxf(v1, 0.f);
        H2U pk2; pk2.h = __builtin_amdgcn_cvt_pkrtz(v0, v1);
        hp[m] = pk2.u;
    }
    {   // T1: thread writes its own row [pos=lane][ch 0..31] as 4x b128
        uint4* row = (uint4*)(L + lane * LSTRIDE);
        row[0] = make_uint4(hp[0],  hp[1],  hp[2],  hp[3]);
        row[1] = make_uint4(hp[4],  hp[5],  hp[6],  hp[7]);
        row[2] = make_uint4(hp[8],  hp[9],  hp[10], hp[11]);
        row[3] = make_uint4(hp[12], hp[13], hp[14], hp[15]);
    }
    __syncthreads();

    // ---- phase 2: layer-2 via 8x mfma_f32_16x16x32_f16 (4 pos-tiles x 2 col-tiles) ----
    int r16 = lane & 15;   // A-row / C-col
    int q4  = lane >> 4;   // k-group / C-row-group
    U4H8 wb20; wb20.u = wf[lane];
    U4H8 wb21; wb21.u = wf[64 + lane];
    float bias0 = b2[r16], bias1 = b2[16 + r16];

    U4H8 afrag[4];
#pragma unroll
    for (int pt = 0; pt < 4; ++pt)
        afrag[pt].u = *(const uint4*)(L + (pt*16 + r16) * LSTRIDE + q4 * 16);

    f32x4 acc[4][2];
#pragma unroll
    for (int pt = 0; pt < 4; ++pt) {
        acc[pt][0] = (f32x4){bias0, bias0, bias0, bias0};
        acc[pt][1] = (f32x4){bias1, bias1, bias1, bias1};
        acc[pt][0] = __builtin_amdgcn_mfma_f32_16x16x32_f16(afrag[pt].h, wb20.h, acc[pt][0], 0, 0, 0);
        acc[pt][1] = __builtin_amdgcn_mfma_f32_16x16x32_f16(afrag[pt].h, wb21.h, acc[pt][1], 0, 0, 0);
    }

    // T2: relu(h2) -> f16 scatter back to [pos][ch] (write-after-read, in-order LDS pipe)
#pragma unroll
    for (int pt = 0; pt < 4; ++pt)
#pragma unroll
        for (int ct = 0; ct < 2; ++ct)
#pragma unroll
            for (int r = 0; r < 4; ++r) {
                int pos = pt*16 + q4*4 + r;
                int j   = r16 + 16*ct;
                _Float16 v = (_Float16)fmaxf(acc[pt][ct][r], 0.f);
                *(_Float16*)(L + pos * LSTRIDE + j * 2) = v;
            }
    __syncthreads();

    // ---- phase 3: layer-3 via 4x mfma (only C-cols 0..2 meaningful; B cols 3..15 zero) ----
    U4H8 wb3; wb3.u = wf[128 + lane];
    f32x4 c3[4];
#pragma unroll
    for (int pt = 0; pt < 4; ++pt) {
        U4H8 a3; a3.u = *(const uint4*)(L + (pt*16 + r16) * LSTRIDE + q4 * 16);
        c3[pt] = __builtin_amdgcn_mfma_f32_16x16x32_f16(a3.h, wb3.h, (f32x4){0.f, 0.f, 0.f, 0.f}, 0, 0, 0);
    }
    // T3: lanes with col<3 write r_c column-rows as b128 to [c][pos] f32 (stride 256B)
    if (r16 < 3) {
#pragma unroll
        for (int pt = 0; pt < 4; ++pt)
            *(f32x4*)(L + r16 * 256 + (pt*16 + q4*4) * 4) = c3[pt];
    }
    __syncthreads();

    // ---- tail: z = r . node[p]; out0 = Wp . [z, node[n]] ----
    float r0 = *(const float*)(L + 0*256 + lane*4);
    float r1 = *(const float*)(L + 1*256 + lane*4);
    float r2 = *(const float*)(L + 2*256 + lane*4);
    float z  = fmaf(r0, pp0, fmaf(r1, pp1, r2 * pp2));

    float* o0 = outb + (size_t)n * 3;
#pragma unroll
    for (int o = 0; o < 3; ++o) {
        float v = Wp[o*4 + 0] * z;
        v = fmaf(Wp[o*4 + 1], qn0, v);
        v = fmaf(Wp[o*4 + 2], qn1, v);
        v = fmaf(Wp[o*4 + 3], qn2, v);
        o0[o] = v;
    }
}

extern "C" void kernel_launch(void* const* d_in, const int* in_sizes, int n_in,
                              void* d_out, int out_size, void* d_ws, size_t ws_size,
                              hipStream_t stream) {
    const float* in = (const float*)d_in[0];
    const float* W1 = (const float*)d_in[1];
    const float* b1 = (const float*)d_in[2];
    const float* W2 = (const float*)d_in[3];
    const float* b2 = (const float*)d_in[4];
    const float* W3 = (const float*)d_in[5];
    // d_in[6] = Wq — provably unused (softmax weights are exactly 1)
    const float* Wp = (const float*)d_in[7];
    float* out = (float*)d_out;

    uint4* wf = (uint4*)d_ws;   // 192 * 16 B = 3 KB scratch
    hipLaunchKernelGGL(prep_weights, dim3(1), dim3(192), 0, stream, W2, W3, wf);

    int blocks = (BATCH * N_NODES) / 256;   // 25000, exact
    hipLaunchKernelGGL(xattn_kernel, dim3(blocks), dim3(256), 0, stream,
                       in, W1, b1, b2, wf, Wp, out);
}

// Round 5
// 96.900 us; speedup vs baseline: 1.9232x; 1.1380x over previous
//
#include <hip/hip_runtime.h>

#define N_NODES 100000
#define BATCH   64
#define MID     32
#define LSTRIDE 80   // LDS row stride (bytes): 16B-aligned, 20 dw -> 2-way (free) bank aliasing

typedef __attribute__((ext_vector_type(2))) __fp16 h2v;
typedef _Float16 __attribute__((ext_vector_type(8))) f16x8;
typedef float __attribute__((ext_vector_type(4))) f32x4;

union H2U  { h2v h; unsigned int u; };
union U4H8 { uint4 u; f16x8 h; };

// k-permutation used by T2's paired h2 layout: LDS f16 col k holds j = jperm(k)
__host__ __device__ __forceinline__ int jperm(int k) { return (k & 1) ? 16 + (k >> 1) : (k >> 1); }

// wf[0..63]   : W2 B-frag col-tile 0      (mfma_f32_16x16x32_f16 B layout)
// wf[64..127] : W2 B-frag col-tile 1
// wf[128..191]: W3 B-frag (cols 0..2, k-rows pre-permuted by jperm; cols 3..15 zero)
// aux[0..47]  : W1 packed f16 pairs  w1p[k*16+m] = pack(W1[k][2m], W1[k][2m+1])
// aux[48..63] : b1 packed f16 pairs
__global__ void prep_weights(const float* __restrict__ W1, const float* __restrict__ b1,
                             const float* __restrict__ W2, const float* __restrict__ W3,
                             uint4* __restrict__ wf, unsigned int* __restrict__ aux) {
    int t = threadIdx.x;
    if (t < 128) {
        int grp = t >> 6, l = t & 63;
        int j = (l & 15) + 16 * grp, k0 = (l >> 4) * 8;
        unsigned int pk[4];
#pragma unroll
        for (int m = 0; m < 4; ++m) {
            H2U a; a.h = __builtin_amdgcn_cvt_pkrtz(W2[(k0 + 2*m) * MID + j],
                                                    W2[(k0 + 2*m + 1) * MID + j]);
            pk[m] = a.u;
        }
        wf[t] = make_uint4(pk[0], pk[1], pk[2], pk[3]);
    } else if (t < 192) {
        int l = t & 63;
        int j = l & 15, k0 = (l >> 4) * 8;
        unsigned int pk[4];
#pragma unroll
        for (int m = 0; m < 4; ++m) {
            int ja = jperm(k0 + 2*m), jb = jperm(k0 + 2*m + 1);
            float x0 = (j < 3) ? W3[ja * 6 + j] : 0.f;
            float x1 = (j < 3) ? W3[jb * 6 + j] : 0.f;
            H2U a; a.h = __builtin_amdgcn_cvt_pkrtz(x0, x1);
            pk[m] = a.u;
        }
        wf[128 + l] = make_uint4(pk[0], pk[1], pk[2], pk[3]);
    } else if (t < 240) {
        int i = t - 192;               // w1p
        int k = i >> 4, m = i & 15;
        H2U a; a.h = __builtin_amdgcn_cvt_pkrtz(W1[k * MID + 2*m], W1[k * MID + 2*m + 1]);
        aux[i] = a.u;
    } else {
        int m = t - 240;               // b1p
        H2U a; a.h = __builtin_amdgcn_cvt_pkrtz(b1[2*m], b1[2*m + 1]);
        aux[48 + m] = a.u;
    }
}

// Softmax is degenerate (dst bijection -> alpha == 1 exactly); q/Wq/key unused.
// Wave-private LDS scratch; per-wave in-order DS pipe -> NO barriers anywhere.
// p-side inputs come from lane-1 via shuffle (edge[n] is loaded anyway for the ch-2 copy).
__global__ __launch_bounds__(256) void xattn_kernel(
    const float* __restrict__ in,
    const unsigned int* __restrict__ aux,   // w1p / b1p
    const float* __restrict__ b2,
    const uint4* __restrict__ wf,
    const float* __restrict__ Wp,
    float* __restrict__ out)
{
    __shared__ uint4 ldsbuf[4 * 64 * LSTRIDE / 16];   // 20480 B
    int tid  = threadIdx.x;
    int lane = tid & 63;
    int wave = tid >> 6;
    char* L = (char*)ldsbuf + wave * (64 * LSTRIDE);

    int idx = blockIdx.x * 256 + tid;     // grid covers exactly B*N
    int b = idx / N_NODES;
    int n = idx - b * N_NODES;

    const float* inb  = in  + (size_t)b * (3u * N_NODES * 3u);
    float*       outb = out + (size_t)b * (3u * N_NODES * 3u);

    const float* nn_ = inb + (size_t)n * 3;                   // node[n]
    const float* c1p = inb + ((size_t)N_NODES + n) * 3;       // ch1[n]
    const float* c2p = inb + ((size_t)2 * N_NODES + n) * 3;   // edge[n]

    float qn0 = nn_[0], qn1 = nn_[1], qn2 = nn_[2];
    float c10 = c1p[0], c11 = c1p[1], c12 = c1p[2];
    float ed0 = c2p[0], ed1 = c2p[1], ed2 = c2p[2];

    // pass-through stores (ch1, ch2)
    {
        float* o1 = outb + ((size_t)N_NODES + n) * 3;
        float* o2 = outb + ((size_t)2 * N_NODES + n) * 3;
        o1[0] = c10; o1[1] = c11; o1[2] = c12;
        o2[0] = ed0; o2[1] = ed1; o2[2] = ed2;
    }

    // p-side data from lane-1; boundary lanes load directly
    float pp0 = __shfl_up(qn0, 1), pp1 = __shfl_up(qn1, 1), pp2 = __shfl_up(qn2, 1);
    float e0  = __shfl_up(ed0, 1), e1  = __shfl_up(ed1, 1), e2  = __shfl_up(ed2, 1);
    if (lane == 0 || n == 0) {
        int p = (n == 0) ? (N_NODES - 1) : (n - 1);
        const float* np_ = inb + (size_t)p * 3;
        const float* epp = inb + ((size_t)2 * N_NODES + p) * 3;
        pp0 = np_[0]; pp1 = np_[1]; pp2 = np_[2];
        e0  = epp[0]; e1  = epp[1]; e2  = epp[2];
    }

    // ---- layer 1: packed f16 (v_pk_fma_f16), relu, -> LDS rows [pos][32 f16] ----
    h2v eh0 = {(__fp16)e0, (__fp16)e0};
    h2v eh1 = {(__fp16)e1, (__fp16)e1};
    h2v eh2 = {(__fp16)e2, (__fp16)e2};
    h2v zz  = {(__fp16)0.0f, (__fp16)0.0f};
    unsigned int hp[16];
#pragma unroll
    for (int m = 0; m < 16; ++m) {
        H2U acc, w0, w1_, w2_;
        acc.u = aux[48 + m];
        w0.u  = aux[m];
        w1_.u = aux[16 + m];
        w2_.u = aux[32 + m];
        acc.h = eh0 * w0.h + acc.h;
        acc.h = eh1 * w1_.h + acc.h;
        acc.h = eh2 * w2_.h + acc.h;
        acc.h = __builtin_elementwise_max(acc.h, zz);
        hp[m] = acc.u;
    }
    {
        uint4* row = (uint4*)(L + lane * LSTRIDE);
        row[0] = make_uint4(hp[0],  hp[1],  hp[2],  hp[3]);
        row[1] = make_uint4(hp[4],  hp[5],  hp[6],  hp[7]);
        row[2] = make_uint4(hp[8],  hp[9],  hp[10], hp[11]);
        row[3] = make_uint4(hp[12], hp[13], hp[14], hp[15]);
    }

    // ---- per pos-tile: layer-2 MFMA -> relu/pack (k-permuted) -> layer-3 MFMA ----
    int r16 = lane & 15;   // A-row within tile / C-col
    int q4  = lane >> 4;   // k-group / C-row-group
    U4H8 wb20; wb20.u = wf[lane];
    U4H8 wb21; wb21.u = wf[64 + lane];
    U4H8 wb3;  wb3.u  = wf[128 + lane];
    float bias0 = b2[r16], bias1 = b2[16 + r16];

#pragma unroll
    for (int pt = 0; pt < 4; ++pt) {
        U4H8 a; a.u = *(const uint4*)(L + (pt*16 + r16) * LSTRIDE + q4 * 16);
        f32x4 acc0 = {bias0, bias0, bias0, bias0};
        f32x4 acc1 = {bias1, bias1, bias1, bias1};
        acc0 = __builtin_amdgcn_mfma_f32_16x16x32_f16(a.h, wb20.h, acc0, 0, 0, 0);
        acc1 = __builtin_amdgcn_mfma_f32_16x16x32_f16(a.h, wb21.h, acc1, 0, 0, 0);

        // T2: pack (j=r16, j=16+r16) -> u32 at [pos][dword r16] (k-permuted layout)
        unsigned int* tb = (unsigned int*)(L + (pt*16 + q4*4) * LSTRIDE) + r16;
#pragma unroll
        for (int r = 0; r < 4; ++r) {
            H2U t;
            t.h = __builtin_amdgcn_cvt_pkrtz(fmaxf(acc0[r], 0.f), fmaxf(acc1[r], 0.f));
            tb[r * (LSTRIDE/4)] = t.u;
        }

        // layer-3 on the same rows (W3 B-frag pre-permuted to match)
        U4H8 a3; a3.u = *(const uint4*)(L + (pt*16 + r16) * LSTRIDE + q4 * 16);
        f32x4 c3 = __builtin_amdgcn_mfma_f32_16x16x32_f16(a3.h, wb3.h, (f32x4){0.f,0.f,0.f,0.f}, 0, 0, 0);

        // T3: r_c rows -> [c][pos] f32 (tile-0 rows already consumed; wave-private)
        if (r16 < 3)
            *(f32x4*)(L + r16 * 256 + (pt*16 + q4*4) * 4) = c3;
    }

    // ---- tail: z = r . node[p]; out0 = Wp . [z, node[n]] ----
    float r0 = *(const float*)(L + 0*256 + lane*4);
    float r1 = *(const float*)(L + 1*256 + lane*4);
    float r2 = *(const float*)(L + 2*256 + lane*4);
    float z  = fmaf(r0, pp0, fmaf(r1, pp1, r2 * pp2));

    float* o0 = outb + (size_t)n * 3;
#pragma unroll
    for (int o = 0; o < 3; ++o) {
        float v = Wp[o*4 + 0] * z;
        v = fmaf(Wp[o*4 + 1], qn0, v);
        v = fmaf(Wp[o*4 + 2], qn1, v);
        v = fmaf(Wp[o*4 + 3], qn2, v);
        o0[o] = v;
    }
}

extern "C" void kernel_launch(void* const* d_in, const int* in_sizes, int n_in,
                              void* d_out, int out_size, void* d_ws, size_t ws_size,
                              hipStream_t stream) {
    const float* in = (const float*)d_in[0];
    const float* W1 = (const float*)d_in[1];
    const float* b1 = (const float*)d_in[2];
    const float* W2 = (const float*)d_in[3];
    const float* b2 = (const float*)d_in[4];
    const float* W3 = (const float*)d_in[5];
    // d_in[6] = Wq — provably unused (softmax weights are exactly 1)
    const float* Wp = (const float*)d_in[7];
    float* out = (float*)d_out;

    uint4* wf = (uint4*)d_ws;                        // 192 * 16 B
    unsigned int* aux = (unsigned int*)(wf + 192);   // 64 * 4 B
    hipLaunchKernelGGL(prep_weights, dim3(1), dim3(256), 0, stream, W1, b1, W2, W3, wf, aux);

    int blocks = (BATCH * N_NODES) / 256;   // 25000, exact
    hipLaunchKernelGGL(xattn_kernel, dim3(blocks), dim3(256), 0, stream,
                       in, aux, b2, wf, Wp, out);
}

// Round 6
// 95.374 us; speedup vs baseline: 1.9540x; 1.0160x over previous
//
#include <hip/hip_runtime.h>

#define N_NODES 100000
#define BATCH   64
#define MID     32
#define LSTRIDE 80   // LDS row stride (bytes): 16B-aligned, 20 dw -> 2-way (free) bank aliasing
#define TOTAL   (BATCH * N_NODES)

typedef __attribute__((ext_vector_type(2))) __fp16 h2v;
typedef _Float16 __attribute__((ext_vector_type(8))) f16x8;
typedef float __attribute__((ext_vector_type(4))) f32x4;
typedef float __attribute__((ext_vector_type(2))) f32x2;

union H2U  { h2v h; unsigned int u; };
union U4H8 { uint4 u; f16x8 h; };

// align-4 vector wrappers: (...,3) f32 layout is only 4B-aligned; gfx9+ global
// dwordx4/dwordx2 loads are legal & fast at align 4.
struct __attribute__((packed, aligned(4))) F4u { f32x4 v; };
struct __attribute__((packed, aligned(4))) F2u { f32x2 v; };

// k-permutation used by T2's paired h2 layout: LDS f16 col k holds j = jperm(k)
__host__ __device__ __forceinline__ int jperm(int k) { return (k & 1) ? 16 + (k >> 1) : (k >> 1); }

// wf[0..63]   : W2 B-frag col-tile 0      (mfma_f32_16x16x32_f16 B layout)
// wf[64..127] : W2 B-frag col-tile 1
// wf[128..191]: W3 B-frag (cols 0..2, k-rows pre-permuted by jperm; cols 3..15 zero)
// aux[0..47]  : W1 packed f16 pairs  w1p[k*16+m] = pack(W1[k][2m], W1[k][2m+1])
// aux[48..63] : b1 packed f16 pairs
__global__ void prep_weights(const float* __restrict__ W1, const float* __restrict__ b1,
                             const float* __restrict__ W2, const float* __restrict__ W3,
                             uint4* __restrict__ wf, unsigned int* __restrict__ aux) {
    int t = threadIdx.x;
    if (t < 128) {
        int grp = t >> 6, l = t & 63;
        int j = (l & 15) + 16 * grp, k0 = (l >> 4) * 8;
        unsigned int pk[4];
#pragma unroll
        for (int m = 0; m < 4; ++m) {
            H2U a; a.h = __builtin_amdgcn_cvt_pkrtz(W2[(k0 + 2*m) * MID + j],
                                                    W2[(k0 + 2*m + 1) * MID + j]);
            pk[m] = a.u;
        }
        wf[t] = make_uint4(pk[0], pk[1], pk[2], pk[3]);
    } else if (t < 192) {
        int l = t & 63;
        int j = l & 15, k0 = (l >> 4) * 8;
        unsigned int pk[4];
#pragma unroll
        for (int m = 0; m < 4; ++m) {
            int ja = jperm(k0 + 2*m), jb = jperm(k0 + 2*m + 1);
            float x0 = (j < 3) ? W3[ja * 6 + j] : 0.f;
            float x1 = (j < 3) ? W3[jb * 6 + j] : 0.f;
            H2U a; a.h = __builtin_amdgcn_cvt_pkrtz(x0, x1);
            pk[m] = a.u;
        }
        wf[128 + l] = make_uint4(pk[0], pk[1], pk[2], pk[3]);
    } else if (t < 240) {
        int i = t - 192;               // w1p
        int k = i >> 4, m = i & 15;
        H2U a; a.h = __builtin_amdgcn_cvt_pkrtz(W1[k * MID + 2*m], W1[k * MID + 2*m + 1]);
        aux[i] = a.u;
    } else {
        int m = t - 240;               // b1p
        H2U a; a.h = __builtin_amdgcn_cvt_pkrtz(b1[2*m], b1[2*m + 1]);
        aux[48 + m] = a.u;
    }
}

// Softmax is degenerate (dst bijection -> alpha == 1 exactly); q/Wq/key unused.
// Wave-private LDS scratch; per-wave in-order DS pipe -> NO barriers anywhere.
// p-side inputs come from lane-1 via shuffle. All global access via overlap-vec4:
// load 16B at n*12 (use 3 of 4); copy stores write the 4th dword too (identical
// value to what the neighbor thread writes -> benign). OOB at buffer tail guarded.
__global__ __launch_bounds__(256) void xattn_kernel(
    const float* __restrict__ in,
    const unsigned int* __restrict__ aux,   // w1p / b1p
    const float* __restrict__ b2,
    const uint4* __restrict__ wf,
    const float* __restrict__ Wp,
    float* __restrict__ out)
{
    __shared__ uint4 ldsbuf[4 * 64 * LSTRIDE / 16];   // 20480 B
    int tid  = threadIdx.x;
    int lane = tid & 63;
    int wave = tid >> 6;
    char* L = (char*)ldsbuf + wave * (64 * LSTRIDE);

    int idx = blockIdx.x * 256 + tid;     // grid covers exactly B*N
    int b = idx / N_NODES;
    int n = idx - b * N_NODES;
    bool last = (idx == TOTAL - 1);       // single thread with 4B-OOB exposure

    const float* inb  = in  + (size_t)b * (3u * N_NODES * 3u);
    float*       outb = out + (size_t)b * (3u * N_NODES * 3u);

    // ---- overlap-vec4 loads: node[n], ch1[n], edge[n] ----
    f32x4 ndv = ((const F4u*)(inb + (size_t)n * 3))->v;
    f32x4 c1v = ((const F4u*)(inb + (size_t)N_NODES * 3 + (size_t)n * 3))->v;
    f32x4 edv;
    const float* e_ptr = inb + (size_t)2 * N_NODES * 3 + (size_t)n * 3;
    if (!last) {
        edv = ((const F4u*)e_ptr)->v;
    } else {
        edv = (f32x4){e_ptr[0], e_ptr[1], e_ptr[2], 0.f};
    }

    float qn0 = ndv.x, qn1 = ndv.y, qn2 = ndv.z;
    float ed0 = edv.x, ed1 = edv.y, ed2 = edv.z;

    // ---- pass-through stores (ch1, ch2) ----
    {
        float* o1p = outb + (size_t)N_NODES * 3 + (size_t)n * 3;
        ((F4u*)o1p)->v = c1v;              // 4th dword = neighbor's identical value
        float* o2p = outb + (size_t)2 * N_NODES * 3 + (size_t)n * 3;
        if (!last) ((F4u*)o2p)->v = edv;
        else { o2p[0] = ed0; o2p[1] = ed1; o2p[2] = ed2; }
    }

    // ---- p-side data from lane-1; boundary lanes load directly ----
    float pp0 = __shfl_up(qn0, 1), pp1 = __shfl_up(qn1, 1), pp2 = __shfl_up(qn2, 1);
    float e0  = __shfl_up(ed0, 1), e1  = __shfl_up(ed1, 1), e2  = __shfl_up(ed2, 1);
    if (lane == 0 || n == 0) {
        int p = (n == 0) ? (N_NODES - 1) : (n - 1);
        const float* np_ = inb + (size_t)p * 3;
        const float* epp = inb + ((size_t)2 * N_NODES + p) * 3;
        pp0 = np_[0]; pp1 = np_[1]; pp2 = np_[2];
        e0  = epp[0]; e1  = epp[1]; e2  = epp[2];
    }

    // ---- layer 1: packed f16 (v_pk_fma_f16), relu, -> LDS rows [pos][32 f16] ----
    h2v eh0 = {(__fp16)e0, (__fp16)e0};
    h2v eh1 = {(__fp16)e1, (__fp16)e1};
    h2v eh2 = {(__fp16)e2, (__fp16)e2};
    h2v zz  = {(__fp16)0.0f, (__fp16)0.0f};
    unsigned int hp[16];
#pragma unroll
    for (int m = 0; m < 16; ++m) {
        H2U acc, w0, w1_, w2_;
        acc.u = aux[48 + m];
        w0.u  = aux[m];
        w1_.u = aux[16 + m];
        w2_.u = aux[32 + m];
        acc.h = eh0 * w0.h + acc.h;
        acc.h = eh1 * w1_.h + acc.h;
        acc.h = eh2 * w2_.h + acc.h;
        acc.h = __builtin_elementwise_max(acc.h, zz);
        hp[m] = acc.u;
    }
    {
        uint4* row = (uint4*)(L + lane * LSTRIDE);
        row[0] = make_uint4(hp[0],  hp[1],  hp[2],  hp[3]);
        row[1] = make_uint4(hp[4],  hp[5],  hp[6],  hp[7]);
        row[2] = make_uint4(hp[8],  hp[9],  hp[10], hp[11]);
        row[3] = make_uint4(hp[12], hp[13], hp[14], hp[15]);
    }

    // ---- per pos-tile: layer-2 MFMA -> pack+relu (k-permuted) -> layer-3 MFMA ----
    int r16 = lane & 15;   // A-row within tile / C-col
    int q4  = lane >> 4;   // k-group / C-row-group
    U4H8 wb20; wb20.u = wf[lane];
    U4H8 wb21; wb21.u = wf[64 + lane];
    U4H8 wb3;  wb3.u  = wf[128 + lane];
    float bias0 = b2[r16], bias1 = b2[16 + r16];

#pragma unroll
    for (int pt = 0; pt < 4; ++pt) {
        U4H8 a; a.u = *(const uint4*)(L + (pt*16 + r16) * LSTRIDE + q4 * 16);
        f32x4 acc0 = {bias0, bias0, bias0, bias0};
        f32x4 acc1 = {bias1, bias1, bias1, bias1};
        acc0 = __builtin_amdgcn_mfma_f32_16x16x32_f16(a.h, wb20.h, acc0, 0, 0, 0);
        acc1 = __builtin_amdgcn_mfma_f32_16x16x32_f16(a.h, wb21.h, acc1, 0, 0, 0);

        // T2: pack (j=r16, j=16+r16) -> u32 at [pos][dword r16]; relu in f16
        // (cvt_pkrtz preserves sign; max(neg,0)=0 either side of the cvt)
        unsigned int* tb = (unsigned int*)(L + (pt*16 + q4*4) * LSTRIDE) + r16;
#pragma unroll
        for (int r = 0; r < 4; ++r) {
            H2U t;
            t.h = __builtin_amdgcn_cvt_pkrtz(acc0[r], acc1[r]);
            t.h = __builtin_elementwise_max(t.h, zz);
            tb[r * (LSTRIDE/4)] = t.u;
        }

        // layer-3 on the same rows (W3 B-frag pre-permuted to match)
        U4H8 a3; a3.u = *(const uint4*)(L + (pt*16 + r16) * LSTRIDE + q4 * 16);
        f32x4 c3 = __builtin_amdgcn_mfma_f32_16x16x32_f16(a3.h, wb3.h, (f32x4){0.f,0.f,0.f,0.f}, 0, 0, 0);

        // T3: r_c rows -> [c][pos] f32 (tile-0 rows already consumed; wave-private)
        if (r16 < 3)
            *(f32x4*)(L + r16 * 256 + (pt*16 + q4*4) * 4) = c3;
    }

    // ---- tail: z = r . node[p]; out0 = Wp . [z, node[n]] ----
    float r0 = *(const float*)(L + 0*256 + lane*4);
    float r1 = *(const float*)(L + 1*256 + lane*4);
    float r2 = *(const float*)(L + 2*256 + lane*4);
    float z  = fmaf(r0, pp0, fmaf(r1, pp1, r2 * pp2));

    float vo[3];
#pragma unroll
    for (int o = 0; o < 3; ++o) {
        float v = Wp[o*4 + 0] * z;
        v = fmaf(Wp[o*4 + 1], qn0, v);
        v = fmaf(Wp[o*4 + 2], qn1, v);
        v = fmaf(Wp[o*4 + 3], qn2, v);
        vo[o] = v;
    }
    float* o0 = outb + (size_t)n * 3;
    ((F2u*)o0)->v = (f32x2){vo[0], vo[1]};   // dwordx2 (align 4) + dword
    o0[2] = vo[2];
}

extern "C" void kernel_launch(void* const* d_in, const int* in_sizes, int n_in,
                              void* d_out, int out_size, void* d_ws, size_t ws_size,
                              hipStream_t stream) {
    const float* in = (const float*)d_in[0];
    const float* W1 = (const float*)d_in[1];
    const float* b1 = (const float*)d_in[2];
    const float* W2 = (const float*)d_in[3];
    const float* b2 = (const float*)d_in[4];
    const float* W3 = (const float*)d_in[5];
    // d_in[6] = Wq — provably unused (softmax weights are exactly 1)
    const float* Wp = (const float*)d_in[7];
    float* out = (float*)d_out;

    uint4* wf = (uint4*)d_ws;                        // 192 * 16 B
    unsigned int* aux = (unsigned int*)(wf + 192);   // 64 * 4 B
    hipLaunchKernelGGL(prep_weights, dim3(1), dim3(256), 0, stream, W1, b1, W2, W3, wf, aux);

    int blocks = TOTAL / 256;   // 25000, exact
    hipLaunchKernelGGL(xattn_kernel, dim3(blocks), dim3(256), 0, stream,
                       in, aux, b2, wf, Wp, out);
}